// Round 9
// baseline (290.471 us; speedup 1.0000x reference)
//
#include <hip/hip_runtime.h>
#include <hip/hip_bf16.h>

#define NT 20000
#define NU 2000
#define HID 256
#define HEADS 8
#define FPH 32
#define E_TT 320000
#define E_UT 100000
#define CAP 80

typedef __attribute__((ext_vector_type(8))) short s16x8;
typedef __attribute__((ext_vector_type(4))) short s16x4;
typedef __attribute__((ext_vector_type(4))) float f32x4;
typedef __attribute__((ext_vector_type(2))) float f32x2;

__device__ inline short f2bf(float f) {
  union { float f; unsigned u; } v; v.f = f;
  unsigned r = v.u + 0x7fff + ((v.u >> 16) & 1);
  return (short)(r >> 16);
}
__device__ inline float bf2f(short s) {
  return __uint_as_float(((unsigned)(unsigned short)s) << 16);
}
__device__ inline unsigned char f2q(float f) {
  return (unsigned char)(__builtin_amdgcn_cvt_pk_fp8_f32(f, f, 0, false) & 0xff);
}

// ------ prep: 4x weight transpose (f32->bf16 [col][k]) + 3x w2 + zero init ----------
__global__ __launch_bounds__(256) void prep(const float* __restrict__ w0,
                                            const float* __restrict__ w1,
                                            const float* __restrict__ w2_,
                                            const float* __restrict__ w3,
                                            short* __restrict__ o0,
                                            short* __restrict__ o1,
                                            short* __restrict__ o2,
                                            short* __restrict__ o3,
                                            const float* __restrict__ wd0,
                                            const float* __restrict__ ar0,
                                            const float* __restrict__ wd1,
                                            const float* __restrict__ ar1,
                                            const float* __restrict__ wd2,
                                            const float* __restrict__ ar2,
                                            float* __restrict__ w2all,
                                            int* __restrict__ tt_deg,
                                            int* __restrict__ ut_deg,
                                            float* __restrict__ g) {
  int z = blockIdx.z;
  if (z < 4) {
    __shared__ float tile[32][33];
    const float* W = (z == 0) ? w0 : (z == 1) ? w1 : (z == 2) ? w2_ : w3;
    short* Wt = (z == 0) ? o0 : (z == 1) ? o1 : (z == 2) ? o2 : o3;
    int bx = blockIdx.x, by = blockIdx.y;
    int tx = threadIdx.x & 31, ty = threadIdx.x >> 5;
#pragma unroll
    for (int i = 0; i < 32; i += 8)
      tile[ty + i][tx] = W[(by * 32 + ty + i) * 256 + bx * 32 + tx];
    __syncthreads();
#pragma unroll
    for (int i = 0; i < 32; i += 8)
      Wt[(bx * 32 + ty + i) * 256 + by * 32 + tx] = f2bf(tile[tx][ty + i]);
  } else if (z == 4) {
    int flat = (blockIdx.y * 8 + blockIdx.x) * 256 + threadIdx.x;
    if (flat >= 3 * 2048) return;
    int e = flat >> 11, idx = flat & 2047;
    const float* wd = (e == 0) ? wd0 : (e == 1) ? wd1 : wd2;
    const float* ar = (e == 0) ? ar0 : (e == 1) ? ar1 : ar2;
    int k = idx >> 3, h = idx & 7;
    float s = 0.f;
#pragma unroll
    for (int f = 0; f < 32; ++f) s += wd[k * 256 + h * 32 + f] * ar[h * 32 + f];
    w2all[flat] = s;
  } else {
    int flat = (blockIdx.y * 8 + blockIdx.x) * 256 + threadIdx.x;  // 0..16383
    for (int i = flat; i < NT; i += 16384) { tt_deg[i] = 0; ut_deg[i] = 0; }
    if (flat < 512) g[flat] = 0.f;
  }
}

// ---- deg count (both graphs) + er-projection matrices M[3][32][8], c[3][8] ---------
__global__ void deg2M(const int* __restrict__ tt_dst, const int* __restrict__ ut_dst,
                      int* __restrict__ tt_deg, int* __restrict__ ut_deg,
                      const float* __restrict__ task_enc_w,
                      const float* __restrict__ task_enc_b,
                      const float* __restrict__ l0_post_w,
                      const float* __restrict__ l0_post_b,
                      const float* __restrict__ w2all,
                      float* __restrict__ M, float* __restrict__ c) {
  int e = blockIdx.x * 256 + threadIdx.x;
  if (e < E_TT) atomicAdd(&tt_deg[tt_dst[e]], 1);
  int e2 = e - E_TT;
  if (e2 >= 0 && e2 < E_UT) atomicAdd(&ut_deg[ut_dst[e2]], 1);
  if (e < 768) {
    int et = e >> 8, j = (e >> 3) & 31, h = e & 7;
    const float* W = (et == 2) ? l0_post_w : task_enc_w;
    const float* w2p = w2all + et * 2048;
    float s = 0.f;
    for (int k = 0; k < 256; ++k) s += W[j * 256 + k] * w2p[k * 8 + h];
    M[e] = s;
  } else if (e < 792) {
    int idx = e - 768, et = idx >> 3, h = idx & 7;
    const float* b = (et == 2) ? l0_post_b : task_enc_b;
    const float* w2p = w2all + et * 2048;
    float s = 0.f;
    for (int k = 0; k < 256; ++k) s += b[k] * w2p[k * 8 + h];
    c[idx] = s;
  }
}

// ---------------- K=32 GEMM body (+ optional colsum, + optional er epilogue) --------
__device__ inline void k32_body(const float* __restrict__ A, const float* __restrict__ W,
                                const float* __restrict__ bias, float* __restrict__ Cf,
                                short* __restrict__ Cb, int N, int blk,
                                float* __restrict__ gsum,
                                const float* __restrict__ M, const float* __restrict__ c,
                                float* __restrict__ er0, float* __restrict__ er1) {
  __shared__ float Ws[32][256];
  __shared__ float Ar[16][32];
  int tid = threadIdx.x;
  for (int i = tid; i < 32 * 256; i += 256) Ws[i >> 8][i & 255] = W[i];
  int n0 = blk * 16;
  int nrows = min(16, N - n0);
  for (int i = tid; i < 512; i += 256) {
    int r = i >> 5, k = i & 31;
    if (r < nrows) Ar[r][k] = A[(size_t)(n0 + r) * 32 + k];
  }
  __syncthreads();
  float b = bias[tid];
  float colacc = 0.f;
  for (int r = 0; r < nrows; ++r) {
    float acc = b;
#pragma unroll
    for (int k = 0; k < 32; ++k) acc += Ar[r][k] * Ws[k][tid];
    size_t o = (size_t)(n0 + r) * 256 + tid;
    if (Cf) Cf[o] = acc;
    if (Cb) Cb[o] = f2bf(acc);
    colacc += acc;
  }
  if (gsum) atomicAdd(&gsum[tid], colacc);
  if (er0) {
    int r = tid >> 4, e = (tid >> 3) & 1, h = tid & 7;
    int n = n0 + r;
    if (r < nrows) {
      const float* Mp = M + e * 256;
      float s = c[e * 8 + h];
#pragma unroll
      for (int j = 0; j < 32; ++j) s += Ar[r][j] * Mp[j * 8 + h];
      (e ? er1 : er0)[n * 8 + h] = s;
    }
  }
}

// merged encoders: usv blocks then task blocks (task part also emits er, er2)
__global__ __launch_bounds__(256) void enc_gemm(const float* __restrict__ uf,
                                                const float* __restrict__ uw,
                                                const float* __restrict__ ub,
                                                float* __restrict__ out_usv,
                                                short* __restrict__ usvh_b,
                                                const float* __restrict__ tf,
                                                const float* __restrict__ tw,
                                                const float* __restrict__ tb,
                                                short* __restrict__ taskh_b,
                                                float* __restrict__ g,
                                                const float* __restrict__ M,
                                                const float* __restrict__ c,
                                                float* __restrict__ er,
                                                float* __restrict__ er2, int nbU) {
  int b = blockIdx.x;
  if (b < nbU)
    k32_body(uf, uw, ub, out_usv, usvh_b, NU, b, g, nullptr, nullptr, nullptr, nullptr);
  else
    k32_body(tf, tw, tb, nullptr, taskh_b, NT, b - nbU, nullptr, M, c, er, er2);
}

// ---- post GEMM: reads precomputed head-mean hm (f32 [N][32]), K=32, -> bf16 --------
__global__ __launch_bounds__(256) void gemm_k32hm(const float* __restrict__ hm,
                                                  const float* __restrict__ hm2,
                                                  const float* __restrict__ W,
                                                  const float* __restrict__ bias,
                                                  short* __restrict__ Cb, int N,
                                                  const float* __restrict__ M1,
                                                  const float* __restrict__ c1,
                                                  float* __restrict__ erOut) {
  __shared__ float Ws[32][256];
  __shared__ float Ar[16][32];
  int tid = threadIdx.x;
  for (int i = tid; i < 32 * 256; i += 256) Ws[i >> 8][i & 255] = W[i];
  int n0 = blockIdx.x * 16;
  int nrows = min(16, N - n0);
  for (int i = tid; i < 512; i += 256) {
    int r = i >> 5, f = i & 31;
    int n = n0 + r;
    float s = 0.f;
    if (r < nrows) {
      s = hm[(size_t)n * 32 + f];
      if (hm2) s += hm2[(size_t)n * 32 + f];
    }
    Ar[r][f] = s;
  }
  __syncthreads();
  float b = bias[tid];
  for (int r = 0; r < nrows; ++r) {
    float acc = b;
#pragma unroll
    for (int k = 0; k < 32; ++k) acc += Ar[r][k] * Ws[k][tid];
    Cb[(size_t)(n0 + r) * 256 + tid] = f2bf(acc);
  }
  if (erOut && tid < 128) {
    int r = tid >> 3, h = tid & 7;
    int n = n0 + r;
    if (r < nrows) {
      float s = c1[h];
#pragma unroll
      for (int j = 0; j < 32; ++j) s += Ar[r][j] * M1[j * 8 + h];
      erOut[n * 8 + h] = s;
    }
  }
}

// ---- direct-load MFMA GEMM: no LDS, wave = 32 rows x 64 cols; fp8/bf16/f32 outs ----
__device__ inline void gemm_dl_body(const short* __restrict__ A,
                                    const short* __restrict__ Wt,
                                    const float* __restrict__ bias,
                                    float* __restrict__ Cf, short* __restrict__ Cb,
                                    unsigned char* __restrict__ Cq,
                                    int N, int relu, float* __restrict__ gsum,
                                    const float* __restrict__ elW,
                                    float* __restrict__ elOut,
                                    int strip) {
  int lane = threadIdx.x & 63;
  int wv = threadIdx.x >> 6;
  int fr = lane & 15, fq = lane >> 4;
  int row0 = strip * 32;
  int col0 = wv * 64;

  f32x4 acc[2][4];
#pragma unroll
  for (int m = 0; m < 2; ++m)
#pragma unroll
    for (int n = 0; n < 4; ++n) acc[m][n] = (f32x4){0.f, 0.f, 0.f, 0.f};

  const int gr0 = row0 + fr, gr1 = row0 + 16 + fr;
  const bool v0 = gr0 < N, v1 = gr1 < N;
  const short* pa0 = A + (size_t)gr0 * 256 + fq * 8;
  const short* pa1 = A + (size_t)gr1 * 256 + fq * 8;
  const short* pb = Wt + (size_t)(col0 + fr) * 256 + fq * 8;

#pragma unroll
  for (int k0 = 0; k0 < 256; k0 += 32) {
    s16x8 a0 = v0 ? *(const s16x8*)(pa0 + k0) : (s16x8){0,0,0,0,0,0,0,0};
    s16x8 a1 = v1 ? *(const s16x8*)(pa1 + k0) : (s16x8){0,0,0,0,0,0,0,0};
    s16x8 b0 = *(const s16x8*)(pb + k0);
    s16x8 b1 = *(const s16x8*)(pb + 16 * 256 + k0);
    s16x8 b2 = *(const s16x8*)(pb + 32 * 256 + k0);
    s16x8 b3 = *(const s16x8*)(pb + 48 * 256 + k0);
    acc[0][0] = __builtin_amdgcn_mfma_f32_16x16x32_bf16(a0, b0, acc[0][0], 0, 0, 0);
    acc[0][1] = __builtin_amdgcn_mfma_f32_16x16x32_bf16(a0, b1, acc[0][1], 0, 0, 0);
    acc[0][2] = __builtin_amdgcn_mfma_f32_16x16x32_bf16(a0, b2, acc[0][2], 0, 0, 0);
    acc[0][3] = __builtin_amdgcn_mfma_f32_16x16x32_bf16(a0, b3, acc[0][3], 0, 0, 0);
    acc[1][0] = __builtin_amdgcn_mfma_f32_16x16x32_bf16(a1, b0, acc[1][0], 0, 0, 0);
    acc[1][1] = __builtin_amdgcn_mfma_f32_16x16x32_bf16(a1, b1, acc[1][1], 0, 0, 0);
    acc[1][2] = __builtin_amdgcn_mfma_f32_16x16x32_bf16(a1, b2, acc[1][2], 0, 0, 0);
    acc[1][3] = __builtin_amdgcn_mfma_f32_16x16x32_bf16(a1, b3, acc[1][3], 0, 0, 0);
  }

  // el epilogue: wave covers heads 2wv, 2wv+1; reduce acc*al over the 16 fr lanes
  if (elOut) {
    float al0 = elW[(2 * wv + 0) * 32 + fr];
    float al1 = elW[(2 * wv + 0) * 32 + 16 + fr];
    float al2 = elW[(2 * wv + 1) * 32 + fr];
    float al3 = elW[(2 * wv + 1) * 32 + 16 + fr];
#pragma unroll
    for (int m = 0; m < 2; ++m) {
#pragma unroll
      for (int r = 0; r < 4; ++r) {
        int row = row0 + m * 16 + fq * 4 + r;
        float p0 = acc[m][0][r] * al0 + acc[m][1][r] * al1;
        float p1 = acc[m][2][r] * al2 + acc[m][3][r] * al3;
        p0 += __shfl_xor(p0, 1); p0 += __shfl_xor(p0, 2);
        p0 += __shfl_xor(p0, 4); p0 += __shfl_xor(p0, 8);
        p1 += __shfl_xor(p1, 1); p1 += __shfl_xor(p1, 2);
        p1 += __shfl_xor(p1, 4); p1 += __shfl_xor(p1, 8);
        if (fr == 0 && row < N) {
          elOut[row * 8 + 2 * wv] = p0;
          elOut[row * 8 + 2 * wv + 1] = p1;
        }
      }
    }
  }

  float bv[4];
#pragma unroll
  for (int n = 0; n < 4; ++n) bv[n] = bias ? bias[col0 + n * 16 + fr] : 0.f;

  float csum[4] = {0.f, 0.f, 0.f, 0.f};
#pragma unroll
  for (int m = 0; m < 2; ++m) {
    int grb = row0 + m * 16 + fq * 4;
#pragma unroll
    for (int r = 0; r < 4; ++r) {
      if (grb + r >= N) continue;
#pragma unroll
      for (int n = 0; n < 4; ++n) {
        float v = acc[m][n][r] + bv[n];
        if (relu) v = fmaxf(v, 0.f);
        size_t o = (size_t)(grb + r) * 256 + col0 + n * 16 + fr;
        if (Cf) Cf[o] = v;
        if (Cb) Cb[o] = f2bf(v);
        if (Cq) Cq[o] = f2q(v);
        csum[n] += v;
      }
    }
  }
  if (gsum) {
#pragma unroll
    for (int n = 0; n < 4; ++n) {
      float s = csum[n];
      s += __shfl_xor(s, 16);
      s += __shfl_xor(s, 32);
      if (fq == 0) atomicAdd(&gsum[col0 + n * 16 + fr], s);
    }
  }
}

__global__ __launch_bounds__(256) void gemm_dl(const short* __restrict__ A,
                                               const short* __restrict__ Wt,
                                               const float* __restrict__ bias,
                                               float* __restrict__ Cf,
                                               short* __restrict__ Cb,
                                               unsigned char* __restrict__ Cq,
                                               int N, int relu, float* __restrict__ gsum,
                                               const float* __restrict__ elW,
                                               float* __restrict__ elOut) {
  gemm_dl_body(A, Wt, bias, Cf, Cb, Cq, N, relu, gsum, elW, elOut, blockIdx.x);
}

// layer-0 dual: tt strips then ut strips (both with el epilogues, fp8 fs outputs)
__global__ __launch_bounds__(256) void gemm_dl_dual(const short* __restrict__ A0,
                                                    const short* __restrict__ Wt0,
                                                    unsigned char* __restrict__ C0q,
                                                    const float* __restrict__ elW0,
                                                    float* __restrict__ el0,
                                                    const short* __restrict__ A1,
                                                    const short* __restrict__ Wt1,
                                                    unsigned char* __restrict__ C1q,
                                                    const float* __restrict__ elW1,
                                                    float* __restrict__ el1,
                                                    int nstr0) {
  if ((int)blockIdx.x < nstr0)
    gemm_dl_body(A0, Wt0, nullptr, nullptr, nullptr, C0q, NT, 0, nullptr, elW0, el0, blockIdx.x);
  else
    gemm_dl_body(A1, Wt1, nullptr, nullptr, nullptr, C1q, NU, 0, nullptr, elW1, el1, blockIdx.x - nstr0);
}

// ---------------- CSR scan + scatter ----------------
__global__ __launch_bounds__(1024) void scan2(const int* __restrict__ d0, int* __restrict__ o0,
                                              int* __restrict__ c0,
                                              const int* __restrict__ d1, int* __restrict__ o1,
                                              int* __restrict__ c1, int n) {
  const int* deg = blockIdx.x ? d1 : d0;
  int* off = blockIdx.x ? o1 : o0;
  int* cursor = blockIdx.x ? c1 : c0;
  int tid = threadIdx.x;
  const int C = 20;
  int base = tid * C;
  int local[C];
  int s = 0;
#pragma unroll
  for (int i = 0; i < C; ++i) {
    int idx = base + i;
    int v = (idx < n) ? deg[idx] : 0;
    local[i] = s;
    s += v;
  }
  int lane = tid & 63, wave = tid >> 6;
  int x = s;
#pragma unroll
  for (int d = 1; d < 64; d <<= 1) {
    int y = __shfl_up(x, d, 64);
    if (lane >= d) x += y;
  }
  __shared__ int wsum[16];
  if (lane == 63) wsum[wave] = x;
  __syncthreads();
  if (wave == 0) {
    int wv = (lane < 16) ? wsum[lane] : 0;
#pragma unroll
    for (int d = 1; d < 16; d <<= 1) {
      int y = __shfl_up(wv, d, 64);
      if (lane >= d) wv += y;
    }
    if (lane < 16) wsum[lane] = wv;
  }
  __syncthreads();
  int waveoff = (wave == 0) ? 0 : wsum[wave - 1];
  int excl = waveoff + x - s;
#pragma unroll
  for (int i = 0; i < C; ++i) {
    int idx = base + i;
    if (idx < n) {
      int o = excl + local[i];
      off[idx] = o;
      cursor[idx] = o;
    }
  }
  if (tid == 1023) off[n] = waveoff + x;
}

__global__ void scat2(const int* __restrict__ tt_src, const int* __restrict__ tt_dst,
                      int* __restrict__ tt_cur, int* __restrict__ tt_srcs,
                      const int* __restrict__ ut_src, const int* __restrict__ ut_dst,
                      int* __restrict__ ut_cur, int* __restrict__ ut_srcs) {
  int e = blockIdx.x * 256 + threadIdx.x;
  if (e < E_TT) {
    int p = atomicAdd(&tt_cur[tt_dst[e]], 1);
    tt_srcs[p] = tt_src[e];
  }
  int e2 = e - E_TT;
  if (e2 >= 0 && e2 < E_UT) {
    int p = atomicAdd(&ut_cur[ut_dst[e2]], 1);
    ut_srcs[p] = ut_src[e2];
  }
}

// -------- fused softmax + aggregation + head-mean, wave/node, fp8 gather ------------
__device__ inline float gat_w(const float* __restrict__ el, int src, int h,
                              float ern, float mh) {
  float l = el[src * 8 + h] + ern;
  l = l >= 0.f ? l : 0.2f * l;
  return __expf(l - mh);
}

__device__ inline void gat_body(const int* __restrict__ offs, const int* __restrict__ srcs,
                                const float* __restrict__ el, const float* __restrict__ er,
                                const unsigned char* __restrict__ fsq,
                                const float* __restrict__ bias0,
                                const float* __restrict__ bias1,
                                float* __restrict__ hmOut, int n, float (*wl)[8]) {
  int lane = threadIdx.x & 63;
  int e0 = offs[n], e1 = offs[n + 1];
  float4 o;
  if (e0 == e1) {
    o = (float4){0.f, 0.f, 0.f, 0.f};
    if (bias0) {
      o = *(const float4*)(bias0 + lane * 4);
      if (bias1) {
        float4 b1 = *(const float4*)(bias1 + lane * 4);
        o.x += b1.x; o.y += b1.y; o.z += b1.z; o.w += b1.w;
      }
    }
  } else {
    int h1 = lane & 7, slot = lane >> 3;
    float ern1 = er[n * 8 + h1];
    float m = -3.4e38f;
    for (int i = e0 + slot; i < e1; i += 8) {
      float l = el[srcs[i] * 8 + h1] + ern1;
      l = l >= 0.f ? l : 0.2f * l;
      int idx = i - e0;
      if (idx < CAP) wl[idx][h1] = l;
      m = fmaxf(m, l);
    }
    m = fmaxf(m, __shfl_xor(m, 8));
    m = fmaxf(m, __shfl_xor(m, 16));
    m = fmaxf(m, __shfl_xor(m, 32));
    float s = 0.f;
    for (int i = e0 + slot; i < e1; i += 8) {
      int idx = i - e0;
      float l;
      if (idx < CAP) l = wl[idx][h1];
      else {
        l = el[srcs[i] * 8 + h1] + ern1;
        l = l >= 0.f ? l : 0.2f * l;
      }
      float w = __expf(l - m);
      if (idx < CAP) wl[idx][h1] = w;
      s += w;
    }
    s += __shfl_xor(s, 8);
    s += __shfl_xor(s, 16);
    s += __shfl_xor(s, 32);
    int h2 = lane >> 3;
    float mh = __shfl(m, h2);
    float sh = __shfl(s, h2);
    float ern2 = __shfl(ern1, h2);
    float ax = 0.f, ay = 0.f, az = 0.f, aw = 0.f;
    int i = e0;
    for (; i + 8 <= e1; i += 8) {
      int sj[8];
      unsigned qj[8];
#pragma unroll
      for (int j = 0; j < 8; ++j) sj[j] = srcs[i + j];
#pragma unroll
      for (int j = 0; j < 8; ++j)
        qj[j] = *(const unsigned*)(fsq + (size_t)sj[j] * 256 + lane * 4);
      int idx = i - e0;
      float wj[8];
      if (idx + 7 < CAP) {
#pragma unroll
        for (int j = 0; j < 8; ++j) wj[j] = wl[idx + j][h2];
      } else {
#pragma unroll
        for (int j = 0; j < 8; ++j)
          wj[j] = (idx + j < CAP) ? wl[idx + j][h2] : gat_w(el, sj[j], h2, ern2, mh);
      }
#pragma unroll
      for (int j = 0; j < 8; ++j) {
        f32x2 lo = __builtin_amdgcn_cvt_pk_f32_fp8(qj[j], false);
        f32x2 up = __builtin_amdgcn_cvt_pk_f32_fp8(qj[j], true);
        ax += wj[j] * lo[0];
        ay += wj[j] * lo[1];
        az += wj[j] * up[0];
        aw += wj[j] * up[1];
      }
    }
    for (; i < e1; ++i) {
      int src = srcs[i];
      int idx = i - e0;
      float w = (idx < CAP) ? wl[idx][h2] : gat_w(el, src, h2, ern2, mh);
      unsigned q = *(const unsigned*)(fsq + (size_t)src * 256 + lane * 4);
      f32x2 lo = __builtin_amdgcn_cvt_pk_f32_fp8(q, false);
      f32x2 up = __builtin_amdgcn_cvt_pk_f32_fp8(q, true);
      ax += w * lo[0];
      ay += w * lo[1];
      az += w * up[0];
      aw += w * up[1];
    }
    float sinv = 1.f / sh;
    o = (float4){ax * sinv, ay * sinv, az * sinv, aw * sinv};
    if (bias0) {
      float4 b = *(const float4*)(bias0 + lane * 4);
      o.x += b.x; o.y += b.y; o.z += b.z; o.w += b.w;
      if (bias1) {
        float4 b1 = *(const float4*)(bias1 + lane * 4);
        o.x += b1.x; o.y += b1.y; o.z += b1.z; o.w += b1.w;
      }
    }
  }
  // head-mean: lanes with same (lane&7) across the 8 head-groups hold the same f block
  o.x += __shfl_xor(o.x, 8); o.x += __shfl_xor(o.x, 16); o.x += __shfl_xor(o.x, 32);
  o.y += __shfl_xor(o.y, 8); o.y += __shfl_xor(o.y, 16); o.y += __shfl_xor(o.y, 32);
  o.z += __shfl_xor(o.z, 8); o.z += __shfl_xor(o.z, 16); o.z += __shfl_xor(o.z, 32);
  o.w += __shfl_xor(o.w, 8); o.w += __shfl_xor(o.w, 16); o.w += __shfl_xor(o.w, 32);
  if (lane < 8) {
    float4 hmv = {o.x * 0.125f, o.y * 0.125f, o.z * 0.125f, o.w * 0.125f};
    *(float4*)(hmOut + (size_t)n * 32 + lane * 4) = hmv;
  }
}

__global__ __launch_bounds__(256) void gat_fused2(
    const int* __restrict__ oA, const int* __restrict__ sA,
    const float* __restrict__ elA, const float* __restrict__ erA,
    const unsigned char* __restrict__ fA,
    const float* __restrict__ b0A, const float* __restrict__ b1A,
    float* __restrict__ hmA, int ndstA, int nA,
    const int* __restrict__ oB, const int* __restrict__ sB,
    const float* __restrict__ elB, const float* __restrict__ erB,
    const unsigned char* __restrict__ fB, float* __restrict__ hmB, int ndstB) {
  __shared__ float wlds[4][CAP][8];
  int wv = threadIdx.x >> 6;
  int b = blockIdx.x;
  if (b < nA) {
    int n = b * 4 + wv;
    if (n >= ndstA) return;
    gat_body(oA, sA, elA, erA, fA, b0A, b1A, hmA, n, wlds[wv]);
  } else {
    int n = (b - nA) * 4 + wv;
    if (n >= ndstB) return;
    gat_body(oB, sB, elB, erB, fB, nullptr, nullptr, hmB, n, wlds[wv]);
  }
}

// ---------------- global projection (with mean scaling) ----------------
__global__ __launch_bounds__(512) void global_proj(const float* __restrict__ g,
                                                   const float* __restrict__ W,
                                                   const float* __restrict__ b,
                                                   float* __restrict__ out) {
  __shared__ float gl[512];
  int tid = threadIdx.x;
  gl[tid] = g[tid] * (tid < 256 ? (1.f / NU) : (1.f / NT));
  __syncthreads();
  float s = b[tid];
  for (int k = 0; k < 512; ++k) s += gl[k] * W[k * 512 + tid];
  out[tid] = s;
}

extern "C" void kernel_launch(void* const* d_in, const int* in_sizes, int n_in,
                              void* d_out, int out_size, void* d_ws, size_t ws_size,
                              hipStream_t stream) {
  const float* usv_feat   = (const float*)d_in[0];
  const float* task_feat  = (const float*)d_in[1];
  const float* usv_enc_w  = (const float*)d_in[2];
  const float* usv_enc_b  = (const float*)d_in[3];
  const float* task_enc_w = (const float*)d_in[4];
  const float* task_enc_b = (const float*)d_in[5];
  const float* l0_tt_wsrc = (const float*)d_in[6];
  const float* l0_tt_wdst = (const float*)d_in[7];
  const float* l0_tt_al   = (const float*)d_in[8];
  const float* l0_tt_ar   = (const float*)d_in[9];
  const float* l0_tt_bias = (const float*)d_in[10];
  const float* l0_ut_wsrc = (const float*)d_in[11];
  const float* l0_ut_wdst = (const float*)d_in[12];
  const float* l0_ut_al   = (const float*)d_in[13];
  const float* l0_ut_ar   = (const float*)d_in[14];
  const float* l0_ut_bias = (const float*)d_in[15];
  const float* l0_post_w  = (const float*)d_in[16];
  const float* l0_post_b  = (const float*)d_in[17];
  const float* l1_tt_wsrc = (const float*)d_in[18];
  const float* l1_tt_wdst = (const float*)d_in[19];
  const float* l1_tt_al   = (const float*)d_in[20];
  const float* l1_tt_ar   = (const float*)d_in[21];
  const float* l1_tt_bias = (const float*)d_in[22];
  const float* l1_post_w  = (const float*)d_in[23];
  const float* l1_post_b  = (const float*)d_in[24];
  const float* task_dec_w = (const float*)d_in[25];
  const float* task_dec_b = (const float*)d_in[26];
  const float* gp_w       = (const float*)d_in[27];
  const float* gp_b       = (const float*)d_in[28];
  const int* tt_src = (const int*)d_in[29];
  const int* tt_dst = (const int*)d_in[30];
  const int* ut_src = (const int*)d_in[31];
  const int* ut_dst = (const int*)d_in[32];

  float* out = (float*)d_out;
  float* out_usv  = out;
  float* out_task = out + NU * HID;
  float* out_glob = out + NU * HID + NT * HID;

  char* ws = (char*)d_ws;
  size_t off = 0;
  auto alloc_f = [&](size_t n) {
    float* p = (float*)(ws + off);
    off += ((n * 4 + 1023) / 1024) * 1024;
    return p;
  };
  auto alloc_i = [&](size_t n) {
    int* p = (int*)(ws + off);
    off += ((n * 4 + 1023) / 1024) * 1024;
    return p;
  };
  auto alloc_s = [&](size_t n) {
    short* p = (short*)(ws + off);
    off += ((n * 2 + 1023) / 1024) * 1024;
    return p;
  };
  auto alloc_b = [&](size_t n) {
    unsigned char* p = (unsigned char*)(ws + off);
    off += ((n + 1023) / 1024) * 1024;
    return p;
  };
  short* taskh_b = alloc_s((size_t)NT * HID);
  short* usvh_b  = alloc_s((size_t)NU * HID);
  unsigned char* fs_q  = alloc_b((size_t)NT * HID);
  unsigned char* fsu_q = alloc_b((size_t)NU * HID);
  float* hm_t  = alloc_f((size_t)NT * FPH);
  float* hm_u  = alloc_f((size_t)NT * FPH);
  float* el    = alloc_f((size_t)NT * HEADS);
  float* er    = alloc_f((size_t)NT * HEADS);
  float* el2   = alloc_f((size_t)NU * HEADS);
  float* er2   = alloc_f((size_t)NT * HEADS);
  float* w2all = alloc_f(3 * 2048);
  float* g     = alloc_f(512);
  float* Mbuf  = alloc_f(768);
  float* cbuf  = alloc_f(24);
  short* wt0 = alloc_s(256 * 256);
  short* wt1 = alloc_s(256 * 256);
  short* wt2 = alloc_s(256 * 256);
  short* wt3 = alloc_s(256 * 256);
  int* tt_deg  = alloc_i(NT);
  int* tt_offs = alloc_i(NT + 1);
  int* tt_cur  = alloc_i(NT);
  int* tt_srcs = alloc_i(E_TT);
  int* ut_deg  = alloc_i(NT);
  int* ut_offs = alloc_i(NT + 1);
  int* ut_cur  = alloc_i(NT);
  int* ut_srcs = alloc_i(E_UT);

  // 1) transposes + w2 + zero init
  prep<<<dim3(8, 8, 6), 256, 0, stream>>>(l0_tt_wsrc, l0_ut_wsrc, l1_tt_wsrc, task_dec_w,
                                          wt0, wt1, wt2, wt3,
                                          l0_tt_wdst, l0_tt_ar, l0_ut_wdst, l0_ut_ar,
                                          l1_tt_wdst, l1_tt_ar, w2all,
                                          tt_deg, ut_deg, g);

  // 2) degree count + er-projection matrices
  int nbE = (E_TT + E_UT + 255) / 256;
  deg2M<<<nbE, 256, 0, stream>>>(tt_dst, ut_dst, tt_deg, ut_deg,
                                 task_enc_w, task_enc_b, l0_post_w, l0_post_b,
                                 w2all, Mbuf, cbuf);

  // 3-4) CSR scan + scatter
  scan2<<<2, 1024, 0, stream>>>(tt_deg, tt_offs, tt_cur, ut_deg, ut_offs, ut_cur, NT);
  scat2<<<nbE, 256, 0, stream>>>(tt_src, tt_dst, tt_cur, tt_srcs, ut_src, ut_dst, ut_cur, ut_srcs);

  // 5) encoders (usv: colsum into g; task: er, er2 epilogue)
  int nbU16 = (NU + 15) / 16, nbT16 = (NT + 15) / 16;
  enc_gemm<<<nbU16 + nbT16, 256, 0, stream>>>(usv_feat, usv_enc_w, usv_enc_b, out_usv, usvh_b,
                                              task_feat, task_enc_w, task_enc_b, taskh_b,
                                              g, Mbuf, cbuf, er, er2, nbU16);

  int nstrT = (NT + 31) / 32, nstrU = (NU + 31) / 32;
  int nbAgg = (NT + 3) / 4;

  // 6) layer 0: both GEMMs + el/el2 epilogues, fp8 fs outputs
  gemm_dl_dual<<<nstrT + nstrU, 256, 0, stream>>>(taskh_b, wt0, fs_q, l0_tt_al, el,
                                                  usvh_b, wt1, fsu_q, l0_ut_al, el2, nstrT);

  // 7) layer 0: both aggregations (tt -> hm_t, ut -> hm_u), head-mean fused
  gat_fused2<<<nbAgg + nbAgg, 256, 0, stream>>>(
      tt_offs, tt_srcs, el, er, fs_q, l0_tt_bias, l0_ut_bias, hm_t, NT, nbAgg,
      ut_offs, ut_srcs, el2, er2, fsu_q, hm_u, NT);

  // 8) post 0 (reads hm_t + hm_u) + er for layer 1
  gemm_k32hm<<<nbT16, 256, 0, stream>>>(hm_t, hm_u, l0_post_w, l0_post_b, taskh_b, NT,
                                        Mbuf + 512, cbuf + 16, er);

  // 9) layer 1 GEMM + el epilogue, fp8 fs output
  gemm_dl<<<nstrT, 256, 0, stream>>>(taskh_b, wt2, nullptr, nullptr, nullptr, fs_q, NT, 0, nullptr,
                                     l1_tt_al, el);

  // 10) layer 1 aggregation (head-mean fused)
  gat_fused2<<<nbAgg, 256, 0, stream>>>(
      tt_offs, tt_srcs, el, er, fs_q, l1_tt_bias, nullptr, hm_t, NT, nbAgg,
      tt_offs, tt_srcs, el, er, fs_q, hm_u, 0);

  // 11) post 1
  gemm_k32hm<<<nbT16, 256, 0, stream>>>(hm_t, nullptr, l1_post_w, l1_post_b, taskh_b, NT,
                                        nullptr, nullptr, nullptr);

  // 12) decoder (relu, f32 out, fused task column sums)
  gemm_dl<<<nstrT, 256, 0, stream>>>(taskh_b, wt3, task_dec_b, out_task, nullptr, nullptr, NT, 1,
                                     g + 256, nullptr, nullptr);

  // 13) global projection
  global_proj<<<1, 512, 0, stream>>>(g, gp_w, gp_b, out_glob);
}